// Round 12
// baseline (225.332 us; speedup 1.0000x reference)
//
#include <hip/hip_runtime.h>
#include <hip/hip_bf16.h>
#include <float.h>

#define C 64
#define H 4
#define HC 256
#define NEG_SLOPE 0.2f
#define EPS_SEG 1e-16f
#define LN_EPS 1e-5f
#define ROWB 576  // xh row: 512B bf16[256] | 16B f32 s_src[4] | 48B pad

typedef __attribute__((ext_vector_type(8))) short bf16x8;
typedef __attribute__((ext_vector_type(4))) float f32x4;

__device__ __forceinline__ float warp_sum(float v) {
#pragma unroll
    for (int m = 32; m >= 1; m >>= 1) v += __shfl_xor(v, m, 64);
    return v;
}

__device__ __forceinline__ unsigned short f2bf(float f) {
    unsigned int u = __float_as_uint(f);
    return (unsigned short)((u + 0x7FFF + ((u >> 16) & 1)) >> 16);  // RNE
}

// ---------------- CSR build (once per call; graph is layer-invariant) -------

__global__ void k_zero(int* __restrict__ a, int n) {
    int i = blockIdx.x * blockDim.x + threadIdx.x;
    int stride = gridDim.x * blockDim.x;
    for (int j = i; j < n; j += stride) a[j] = 0;
}

__global__ void k_count(const int* __restrict__ ei, int* __restrict__ counts,
                        int E, int Etot) {
    int eid = blockIdx.x * blockDim.x + threadIdx.x;
    if (eid >= Etot) return;
    int d = (eid < E) ? ei[E + eid] : eid - E;
    atomicAdd(&counts[d], 1);
}

__global__ __launch_bounds__(256) void k_scan1(const int* __restrict__ counts,
                                               int* __restrict__ tmp,
                                               int* __restrict__ bsum, int N) {
    __shared__ int sm[256];
    int t = threadIdx.x;
    int i = blockIdx.x * 256 + t;
    sm[t] = (i < N) ? counts[i] : 0;
    __syncthreads();
    for (int off = 1; off < 256; off <<= 1) {
        int add = (t >= off) ? sm[t - off] : 0;
        __syncthreads();
        sm[t] += add;
        __syncthreads();
    }
    if (i < N) tmp[i] = sm[t];
    if (t == 255) bsum[blockIdx.x] = sm[255];
}

__global__ __launch_bounds__(256) void k_scan2(int* __restrict__ bsum, int nb) {
    __shared__ int sm[256];
    int t = threadIdx.x;
    sm[t] = (t < nb) ? bsum[t] : 0;
    __syncthreads();
    for (int off = 1; off < 256; off <<= 1) {
        int add = (t >= off) ? sm[t - off] : 0;
        __syncthreads();
        sm[t] += add;
        __syncthreads();
    }
    if (t < nb) bsum[t] = (t > 0) ? sm[t - 1] : 0;  // exclusive
}

__global__ __launch_bounds__(256) void k_scan3(const int* __restrict__ tmp,
                                               const int* __restrict__ boff,
                                               int* __restrict__ rowptr,
                                               int* __restrict__ cursor, int N) {
    int i = blockIdx.x * 256 + threadIdx.x;
    if (i < N) {
        rowptr[i + 1] = tmp[i] + boff[blockIdx.x];
        cursor[i] = 0;
    }
    if (i == 0) rowptr[0] = 0;
}

__global__ void k_fill(const int* __restrict__ ei, const int* __restrict__ rowptr,
                       int* __restrict__ cursor, int* __restrict__ col,
                       int E, int Etot) {
    int eid = blockIdx.x * blockDim.x + threadIdx.x;
    if (eid >= Etot) return;
    int s, d;
    if (eid < E) { s = ei[eid]; d = ei[E + eid]; } else { s = d = eid - E; }
    int pos = rowptr[d] + atomicAdd(&cursor[d], 1);
    col[pos] = s;
}

// ---------------- per-layer kernels ----------------------------------------

// f32 [N][C] -> bf16 [Npad][C] (pad rows zeroed); layer-0 only.
__global__ void k_prep_x(const float4* __restrict__ xin, ushort4* __restrict__ xb,
                         int n4, int npad4) {
    int i = blockIdx.x * blockDim.x + threadIdx.x;
    int st = gridDim.x * blockDim.x;
    for (int j = i; j < npad4; j += st) {
        ushort4 o;
        if (j < n4) {
            float4 v = xin[j];
            o.x = f2bf(v.x); o.y = f2bf(v.y); o.z = f2bf(v.z); o.w = f2bf(v.w);
        } else {
            o.x = o.y = o.z = o.w = 0;
        }
        xb[j] = o;
    }
}

// All weight transposes (Wg + W1 + W2, both layers) in one launch.
__global__ void k_prep_weights(const float* __restrict__ Wg,
                               const float* __restrict__ W1, const float* __restrict__ W2,
                               unsigned short* __restrict__ Wgt,
                               unsigned short* __restrict__ W1t,
                               unsigned short* __restrict__ W2t, int L) {
    int i = blockIdx.x * 256 + threadIdx.x;
    int nWg = L * C * HC;
    int nW = L * C * C;
    if (i < nWg) {
        int l = i / (C * HC);
        int r = i - l * C * HC;
        int n = r >> 6, k = r & 63;
        Wgt[(size_t)l * HC * C + n * C + k] = f2bf(Wg[(size_t)l * C * HC + k * HC + n]);
    } else if (i < nWg + nW) {
        int j = i - nWg;
        int l = j / (C * C);
        int r = j - l * C * C;
        int n = r >> 6, k = r & 63;
        W1t[(size_t)l * C * C + n * C + k] = f2bf(W1[(size_t)l * C * C + k * C + n]);
        W2t[(size_t)l * C * C + n * C + k] = f2bf(W2[(size_t)l * C * C + k * C + n]);
    }
}

// xh = xb @ Wg via MFMA; epilogue writes bf16 xh + f32 s_src into 576B rows
// and s_dst to a dense array. Wave w == head w owns cols [64w,64w+64).
__global__ __launch_bounds__(256) void k_gemm_mfma(
    const unsigned short* __restrict__ xb, const unsigned short* __restrict__ Wgt,
    const float* __restrict__ a_src, const float* __restrict__ a_dst,
    char* __restrict__ xhs, float* __restrict__ s_dst, int N)
{
    int w = threadIdx.x >> 6, l = threadIdx.x & 63;
    int n0 = blockIdx.x * 64;
    int lr = l & 15, lk = (l >> 4) * 8;
    bf16x8 bfr[4][2];
    float as[4], ad[4];
#pragma unroll
    for (int ct = 0; ct < 4; ct++) {
        int colg = w * 64 + ct * 16 + lr;
#pragma unroll
        for (int ks = 0; ks < 2; ks++)
            bfr[ct][ks] = *reinterpret_cast<const bf16x8*>(Wgt + colg * C + ks * 32 + lk);
        as[ct] = a_src[w * C + ct * 16 + lr];
        ad[ct] = a_dst[w * C + ct * 16 + lr];
    }
#pragma unroll
    for (int rt = 0; rt < 4; rt++) {
        const unsigned short* arow = xb + (size_t)(n0 + rt * 16 + lr) * C + lk;
        bf16x8 a0 = *reinterpret_cast<const bf16x8*>(arow);
        bf16x8 a1 = *reinterpret_cast<const bf16x8*>(arow + 32);
        f32x4 acc[4];
#pragma unroll
        for (int ct = 0; ct < 4; ct++) {
            acc[ct] = (f32x4){0.f, 0.f, 0.f, 0.f};
            acc[ct] = __builtin_amdgcn_mfma_f32_16x16x32_bf16(a0, bfr[ct][0], acc[ct], 0, 0, 0);
            acc[ct] = __builtin_amdgcn_mfma_f32_16x16x32_bf16(a1, bfr[ct][1], acc[ct], 0, 0, 0);
        }
        int nbase = n0 + rt * 16 + (l >> 4) * 4;
#pragma unroll
        for (int ct = 0; ct < 4; ct++) {
            int cb = (w * 64 + ct * 16 + lr) * 2;
#pragma unroll
            for (int r = 0; r < 4; r++) {
                int n = nbase + r;
                if (n < N)
                    *(unsigned short*)(xhs + (size_t)n * ROWB + cb) = f2bf(acc[ct][r]);
            }
        }
#pragma unroll
        for (int r = 0; r < 4; r++) {
            float ps = acc[0][r] * as[0] + acc[1][r] * as[1]
                     + acc[2][r] * as[2] + acc[3][r] * as[3];
            float pd = acc[0][r] * ad[0] + acc[1][r] * ad[1]
                     + acc[2][r] * ad[2] + acc[3][r] * ad[3];
#pragma unroll
            for (int off = 1; off < 16; off <<= 1) {
                ps += __shfl_xor(ps, off, 64);
                pd += __shfl_xor(pd, off, 64);
            }
            int n = nbase + r;
            if (lr == 0 && n < N) {
                *(float*)(xhs + (size_t)n * ROWB + 512 + w * 4) = ps;
                s_dst[n * H + w] = pd;
            }
        }
    }
}

// 4 nodes per wave, 16 lanes per node (il = lane&15). Per edge-slot each lane
// loads 2x uint4 (32B; group covers the full 512B row) + broadcast float4
// scores. A/B register double-buffer (2-deep pipeline). Lane covers channels
// (il&7)*8..+7 of heads {il>>3, 2+(il>>3)}; partner lane il^8 has the other
// two heads. Epilogue: pair-exchange + 16-lane shuffle LN (channels counted
// twice -> 1/128 normalizers).
__global__ __launch_bounds__(256) void k_gat_node(
    const int* __restrict__ rowptr, const int* __restrict__ col,
    const float* __restrict__ s_dst, const char* __restrict__ xhs,
    const float* __restrict__ x_in, const float* __restrict__ bias,
    const float* __restrict__ g, const float* __restrict__ b,
    float* __restrict__ x1, unsigned short* __restrict__ x1b, int N)
{
    int l = threadIdx.x & 63;
    int il = l & 15;
    int n = blockIdx.x * 16 + ((threadIdx.x >> 6) << 2) + (l >> 4);
    bool nvalid = n < N;
    int nn = nvalid ? n : 0;
    int r0 = rowptr[nn];
    int r1 = rowptr[nn + 1];
    int deg = nvalid ? (r1 - r0) : 0;

    int hsel = (il >> 3) & 1;
    float sdA = s_dst[nn * H + hsel];
    float sdB = s_dst[nn * H + 2 + hsel];
    int c0 = (il & 7) * 8;
    int byteoff = il * 16;

    float acc0[8], acc1[8];
#pragma unroll
    for (int k = 0; k < 8; k++) { acc0[k] = 0.f; acc1[k] = 0.f; }
    float zA = 0.f, zB = 0.f;

    uint4 a0v = {0,0,0,0}, a1v = {0,0,0,0};
    float4 asv = {0.f,0.f,0.f,0.f};
    bool actA = 0 < deg;
    if (actA) {
        const char* p = xhs + (size_t)col[r0] * ROWB;
        a0v = *(const uint4*)(p + byteoff);
        a1v = *(const uint4*)(p + 256 + byteoff);
        asv = *(const float4*)(p + 512);
    }

#define GAT_COMPUTE(V0, V1, SV, ACT)                                          \
    {                                                                         \
        float ea = (hsel ? (SV).y : (SV).x) + sdA;                            \
        float eb = (hsel ? (SV).w : (SV).z) + sdB;                            \
        float wA = (ACT) ? __expf(fmaxf(ea, NEG_SLOPE * ea)) : 0.f;           \
        float wB = (ACT) ? __expf(fmaxf(eb, NEG_SLOPE * eb)) : 0.f;           \
        unsigned int uu0[4] = {(V0).x, (V0).y, (V0).z, (V0).w};               \
        unsigned int uu1[4] = {(V1).x, (V1).y, (V1).z, (V1).w};               \
        _Pragma("unroll")                                                     \
        for (int q = 0; q < 4; q++) {                                         \
            acc0[2*q]   += wA * __uint_as_float(uu0[q] << 16);                \
            acc0[2*q+1] += wA * __uint_as_float(uu0[q] & 0xFFFF0000u);        \
            acc1[2*q]   += wB * __uint_as_float(uu1[q] << 16);                \
            acc1[2*q+1] += wB * __uint_as_float(uu1[q] & 0xFFFF0000u);        \
        }                                                                     \
        zA += wA; zB += wB;                                                   \
    }

    int t = 0;
    while (__any(actA)) {
        bool actB = (t + 1) < deg;
        uint4 b0v = {0,0,0,0}, b1v = {0,0,0,0};
        float4 bsv = {0.f,0.f,0.f,0.f};
        if (actB) {
            const char* p = xhs + (size_t)col[r0 + t + 1] * ROWB;
            b0v = *(const uint4*)(p + byteoff);
            b1v = *(const uint4*)(p + 256 + byteoff);
            bsv = *(const float4*)(p + 512);
        }
        GAT_COMPUTE(a0v, a1v, asv, actA);
        actA = (t + 2) < deg;
        if (actA) {
            const char* p = xhs + (size_t)col[r0 + t + 2] * ROWB;
            a0v = *(const uint4*)(p + byteoff);
            a1v = *(const uint4*)(p + 256 + byteoff);
            asv = *(const float4*)(p + 512);
        } else {
            a0v = (uint4){0,0,0,0}; a1v = (uint4){0,0,0,0};
            asv = (float4){0.f,0.f,0.f,0.f};
        }
        GAT_COMPUTE(b0v, b1v, bsv, actB);
        t += 2;
    }
#undef GAT_COMPUTE

    // head combine: t0 = accA/zA + accB/zB, + partner (il^8), * 1/4
    float izA = 1.f / (zA + EPS_SEG);
    float izB = 1.f / (zB + EPS_SEG);
    float y[8];
#pragma unroll
    for (int k = 0; k < 8; k++) {
        float v = acc0[k] * izA + acc1[k] * izB;
        v += __shfl_xor(v, 8, 64);
        y[k] = v * 0.25f;
    }
    // residual + bias
    float xi[8], bi[8];
    *(float4*)&xi[0] = *(const float4*)(x_in + (size_t)nn * C + c0);
    *(float4*)&xi[4] = *(const float4*)(x_in + (size_t)nn * C + c0 + 4);
    *(float4*)&bi[0] = *(const float4*)(bias + c0);
    *(float4*)&bi[4] = *(const float4*)(bias + c0 + 4);
#pragma unroll
    for (int k = 0; k < 8; k++) y[k] += xi[k] + bi[k];
    // LN over 64 channels (each appears on 2 lanes -> 1/128)
    float s = 0.f;
#pragma unroll
    for (int k = 0; k < 8; k++) s += y[k];
#pragma unroll
    for (int off = 1; off <= 8; off <<= 1) s += __shfl_xor(s, off, 64);
    float mu = s * (1.f / 128.f);
    float vs = 0.f;
    float dv[8];
#pragma unroll
    for (int k = 0; k < 8; k++) { dv[k] = y[k] - mu; vs += dv[k] * dv[k]; }
#pragma unroll
    for (int off = 1; off <= 8; off <<= 1) vs += __shfl_xor(vs, off, 64);
    float rs = rsqrtf(vs * (1.f / 128.f) + LN_EPS);
    if (il < 8 && nvalid) {
        float gg[8], bb[8];
        *(float4*)&gg[0] = *(const float4*)(g + c0);
        *(float4*)&gg[4] = *(const float4*)(g + c0 + 4);
        *(float4*)&bb[0] = *(const float4*)(b + c0);
        *(float4*)&bb[4] = *(const float4*)(b + c0 + 4);
        float o[8];
        ushort4 ob0, ob1;
#pragma unroll
        for (int k = 0; k < 8; k++) o[k] = dv[k] * rs * gg[k] + bb[k];
        *(float4*)(x1 + (size_t)n * C + c0) = *(float4*)&o[0];
        *(float4*)(x1 + (size_t)n * C + c0 + 4) = *(float4*)&o[4];
        ob0.x = f2bf(o[0]); ob0.y = f2bf(o[1]); ob0.z = f2bf(o[2]); ob0.w = f2bf(o[3]);
        ob1.x = f2bf(o[4]); ob1.y = f2bf(o[5]); ob1.z = f2bf(o[6]); ob1.w = f2bf(o[7]);
        *(ushort4*)(x1b + (size_t)n * C + c0) = ob0;
        *(ushort4*)(x1b + (size_t)n * C + c0 + 4) = ob1;
    }
}

// FFN via MFMA: block = 64 nodes, wave w owns rows [16w,16w+16).
__global__ __launch_bounds__(256) void k_ffn_mfma(
    const float* __restrict__ x1f, const unsigned short* __restrict__ x1b,
    const unsigned short* __restrict__ W1t, const unsigned short* __restrict__ W2t,
    const float* __restrict__ b1, const float* __restrict__ b2,
    const float* __restrict__ g, const float* __restrict__ b,
    float* __restrict__ xout, unsigned short* __restrict__ xb, int N)
{
    __shared__ unsigned short hls[64 * 64];  // 8 KB
    int w = threadIdx.x >> 6, l = threadIdx.x & 63;
    int lr = l & 15, q = l >> 4, lk = q * 8;
    int n0 = blockIdx.x * 64;

    // ---- phase 1: h = relu(x @ W1 + b1) ----
    {
        bf16x8 bf[4][2];
#pragma unroll
        for (int ct = 0; ct < 4; ct++)
#pragma unroll
            for (int ks = 0; ks < 2; ks++)
                bf[ct][ks] = *reinterpret_cast<const bf16x8*>(
                    W1t + (ct * 16 + lr) * C + ks * 32 + lk);
        const unsigned short* arow = x1b + (size_t)(n0 + w * 16 + lr) * C + lk;
        bf16x8 a0 = *reinterpret_cast<const bf16x8*>(arow);
        bf16x8 a1 = *reinterpret_cast<const bf16x8*>(arow + 32);
        f32x4 acc[4];
#pragma unroll
        for (int ct = 0; ct < 4; ct++) {
            acc[ct] = (f32x4){0.f, 0.f, 0.f, 0.f};
            acc[ct] = __builtin_amdgcn_mfma_f32_16x16x32_bf16(a0, bf[ct][0], acc[ct], 0, 0, 0);
            acc[ct] = __builtin_amdgcn_mfma_f32_16x16x32_bf16(a1, bf[ct][1], acc[ct], 0, 0, 0);
        }
#pragma unroll
        for (int ct = 0; ct < 4; ct++) {
            float bc = b1[ct * 16 + lr];
#pragma unroll
            for (int r = 0; r < 4; r++) {
                float v = fmaxf(acc[ct][r] + bc, 0.f);
                int rowb = w * 16 + q * 4 + r;
                int byte = rowb * 128 + (ct * 16 + lr) * 2;
                byte ^= (rowb & 7) << 4;
                *(unsigned short*)((char*)hls + byte) = f2bf(v);
            }
        }
    }
    __syncthreads();

    // ---- phase 2: y = h @ W2 + b2 + x1, then LN ----
    bf16x8 bf[4][2];
#pragma unroll
    for (int ct = 0; ct < 4; ct++)
#pragma unroll
        for (int ks = 0; ks < 2; ks++)
            bf[ct][ks] = *reinterpret_cast<const bf16x8*>(
                W2t + (ct * 16 + lr) * C + ks * 32 + lk);
    bf16x8 h0, h1;
    {
        int rowb = w * 16 + lr;
        int swz = (rowb & 7) << 4;
        int byte0 = (rowb * 128 + q * 16) ^ swz;
        int byte1 = (rowb * 128 + 64 + q * 16) ^ swz;
        h0 = *(bf16x8*)((char*)hls + byte0);
        h1 = *(bf16x8*)((char*)hls + byte1);
    }
    f32x4 acc[4];
#pragma unroll
    for (int ct = 0; ct < 4; ct++) {
        acc[ct] = (f32x4){0.f, 0.f, 0.f, 0.f};
        acc[ct] = __builtin_amdgcn_mfma_f32_16x16x32_bf16(h0, bf[ct][0], acc[ct], 0, 0, 0);
        acc[ct] = __builtin_amdgcn_mfma_f32_16x16x32_bf16(h1, bf[ct][1], acc[ct], 0, 0, 0);
    }

    float b2c[4], gc[4], bc[4];
#pragma unroll
    for (int ct = 0; ct < 4; ct++) {
        int cg = ct * 16 + lr;
        b2c[ct] = b2[cg]; gc[ct] = g[cg]; bc[ct] = b[cg];
    }
    float yv[4][4];  // [ct][r]
#pragma unroll
    for (int r = 0; r < 4; r++) {
        int n = n0 + w * 16 + q * 4 + r;
        bool ok = n < N;
#pragma unroll
        for (int ct = 0; ct < 4; ct++) {
            float xr = ok ? x1f[(size_t)n * C + ct * 16 + lr] : 0.f;
            yv[ct][r] = acc[ct][r] + b2c[ct] + xr;
        }
    }
#pragma unroll
    for (int r = 0; r < 4; r++) {
        int n = n0 + w * 16 + q * 4 + r;
        float s = yv[0][r] + yv[1][r] + yv[2][r] + yv[3][r];
#pragma unroll
        for (int off = 1; off < 16; off <<= 1) s += __shfl_xor(s, off, 64);
        float mu = s * (1.f / C);
        float d0 = yv[0][r] - mu, d1 = yv[1][r] - mu;
        float d2 = yv[2][r] - mu, d3 = yv[3][r] - mu;
        float vs = d0 * d0 + d1 * d1 + d2 * d2 + d3 * d3;
#pragma unroll
        for (int off = 1; off < 16; off <<= 1) vs += __shfl_xor(vs, off, 64);
        float rs = rsqrtf(vs * (1.f / C) + LN_EPS);
        if (n < N) {
            float dd[4] = {d0, d1, d2, d3};
#pragma unroll
            for (int ct = 0; ct < 4; ct++) {
                float o = dd[ct] * rs * gc[ct] + bc[ct];
                xout[(size_t)n * C + ct * 16 + lr] = o;
                xb[(size_t)n * C + ct * 16 + lr] = f2bf(o);
            }
        }
    }
}

extern "C" void kernel_launch(void* const* d_in, const int* in_sizes, int n_in,
                              void* d_out, int out_size, void* d_ws, size_t ws_size,
                              hipStream_t stream) {
    const float* x        = (const float*)d_in[0];
    const int*   ei       = (const int*)d_in[1];
    const float* Wg       = (const float*)d_in[2];
    const float* a_src    = (const float*)d_in[3];
    const float* a_dst    = (const float*)d_in[4];
    const float* att_bias = (const float*)d_in[5];
    const float* ln1_g    = (const float*)d_in[6];
    const float* ln1_b    = (const float*)d_in[7];
    const float* W1       = (const float*)d_in[8];
    const float* b1       = (const float*)d_in[9];
    const float* W2       = (const float*)d_in[10];
    const float* b2       = (const float*)d_in[11];
    const float* ln2_g    = (const float*)d_in[12];
    const float* ln2_b    = (const float*)d_in[13];
    float* xout = (float*)d_out;

    int N = in_sizes[0] / C;
    int E = in_sizes[1] / 2;
    int Etot = E + N;
    int L = in_sizes[2] / (C * HC);
    int nb = (N + 255) / 256;
    int Npad = (N + 63) & ~63;

    char* p = (char*)d_ws;
    auto alloc = [&](size_t bytes) { void* r = (void*)p; p += (bytes + 255) & ~(size_t)255; return r; };
    float* s_dst = (float*)alloc((size_t)N * H * 4);
    float* x1    = (float*)alloc((size_t)N * C * 4);
    int* rowptr  = (int*)alloc((size_t)(N + 1) * 4);
    int* col     = (int*)alloc((size_t)Etot * 4);
    int* counts  = (int*)alloc((size_t)N * 4);
    int* tmp     = (int*)alloc((size_t)N * 4);
    int* bsum    = (int*)alloc((size_t)nb * 4);
    unsigned short* xb  = (unsigned short*)alloc((size_t)Npad * C * 2);
    unsigned short* x1b = (unsigned short*)alloc((size_t)Npad * C * 2);
    unsigned short* Wgt = (unsigned short*)alloc((size_t)L * HC * C * 2);
    unsigned short* W1t = (unsigned short*)alloc((size_t)L * C * C * 2);
    unsigned short* W2t = (unsigned short*)alloc((size_t)L * C * C * 2);
    char* xhs = (char*)alloc((size_t)N * ROWB);

    // ---- CSR build (graph identical across layers) ----
    k_zero<<<256, 256, 0, stream>>>(counts, N);
    k_count<<<(Etot + 255) / 256, 256, 0, stream>>>(ei, counts, E, Etot);
    k_scan1<<<nb, 256, 0, stream>>>(counts, tmp, bsum, N);
    k_scan2<<<1, 256, 0, stream>>>(bsum, nb);
    k_scan3<<<nb, 256, 0, stream>>>(tmp, bsum, rowptr, counts, N);
    k_fill<<<(Etot + 255) / 256, 256, 0, stream>>>(ei, rowptr, counts, col, E, Etot);
    k_prep_x<<<2048, 256, 0, stream>>>((const float4*)x, (ushort4*)xb,
                                       N * C / 4, Npad * C / 4);
    {
        int tot = L * C * HC + L * C * C;
        k_prep_weights<<<(tot + 255) / 256, 256, 0, stream>>>(Wg, W1, W2, Wgt, W1t, W2t, L);
    }

    for (int l = 0; l < L; l++) {
        const float* xin = (l == 0) ? x : xout;
        k_gemm_mfma<<<Npad / 64, 256, 0, stream>>>(
            xb, Wgt + (size_t)l * HC * C, a_src + l * H * C, a_dst + l * H * C,
            xhs, s_dst, N);
        k_gat_node<<<(N + 15) / 16, 256, 0, stream>>>(
            rowptr, col, s_dst, xhs, xin,
            att_bias + l * C, ln1_g + l * C, ln1_b + l * C, x1, x1b, N);
        k_ffn_mfma<<<Npad / 64, 256, 0, stream>>>(
            x1, x1b, W1t + (size_t)l * C * C, W2t + (size_t)l * C * C,
            b1 + l * C, b2 + l * C, ln2_g + l * C, ln2_b + l * C, xout, xb, N);
    }
}